// Round 3
// baseline (757.911 us; speedup 1.0000x reference)
//
#include <hip/hip_runtime.h>
#include <hip/hip_bf16.h>

// Problem constants (Head_24799141167224)
// Device buffers: inputs fp32, output fp32 (comparison done at bf16 precision,
// 2% threshold). Evidence: R1 bf16-read -> NaN (fp32 bits as bf16);
// R2 bf16-write -> exact stub absmax (upper half of fp32 out buffer unwritten).
#define NB 4
#define NT 4096
#define NC 2048
#define ND 128
#define NK 409      // int(0.1 * 4096)
#define KPAD 416

// ---------------------------------------------------------------------------
// Kernel 1: q = index @ Wq, fp32 in/accum/out.
// Tiled SGEMM: BM=64, BN=128(=full N), BK=16, 256 threads, 4x8 micro-tile.
// fp32 accumulation: vs np ref the sum-order error is ~1e-6, far below the
// ~1e-3 order-stat gap at rank 409 -> top-k set matches exactly.
// ---------------------------------------------------------------------------
__global__ __launch_bounds__(256) void qgemm_kernel(
    const float* __restrict__ A, const float* __restrict__ Bw,
    float* __restrict__ Cq)
{
    __shared__ float As[16][64];    // [k][m] transposed for float4 inner reads
    __shared__ float Bs[16][128];   // [k][n]
    const int tid = threadIdx.x;
    const int m0 = blockIdx.x * 64;
    const int ty = tid >> 4, tx = tid & 15;
    const int rowb = ty * 4, colb = tx * 8;
    // A staging: 64 rows x 16 k, one float4 per thread
    const int ar = tid >> 2, ak = (tid & 3) * 4;
    // B staging: 16 k x 128 n, 8 elems (2x float4) per thread
    const int bk = tid >> 4, bc = (tid & 15) * 8;

    float acc[4][8];
    #pragma unroll
    for (int r = 0; r < 4; ++r)
        #pragma unroll
        for (int c = 0; c < 8; ++c) acc[r][c] = 0.f;

    const float* aptr = A + (size_t)(m0 + ar) * NC + ak;
    const float* bptr = Bw + (size_t)bk * ND + bc;

    for (int k0 = 0; k0 < NC; k0 += 16) {
        float4 av = *(const float4*)(aptr + k0);
        float4 b0 = *(const float4*)(bptr + (size_t)k0 * ND);
        float4 b1 = *(const float4*)(bptr + (size_t)k0 * ND + 4);
        As[ak + 0][ar] = av.x;
        As[ak + 1][ar] = av.y;
        As[ak + 2][ar] = av.z;
        As[ak + 3][ar] = av.w;
        Bs[bk][bc + 0] = b0.x;
        Bs[bk][bc + 1] = b0.y;
        Bs[bk][bc + 2] = b0.z;
        Bs[bk][bc + 3] = b0.w;
        Bs[bk][bc + 4] = b1.x;
        Bs[bk][bc + 5] = b1.y;
        Bs[bk][bc + 6] = b1.z;
        Bs[bk][bc + 7] = b1.w;
        __syncthreads();
        #pragma unroll
        for (int kk = 0; kk < 16; ++kk) {
            float4 a  = *(const float4*)&As[kk][rowb];
            float4 v0 = *(const float4*)&Bs[kk][colb];
            float4 v1 = *(const float4*)&Bs[kk][colb + 4];
            float ra[4] = {a.x, a.y, a.z, a.w};
            float rb[8] = {v0.x, v0.y, v0.z, v0.w, v1.x, v1.y, v1.z, v1.w};
            #pragma unroll
            for (int r = 0; r < 4; ++r)
                #pragma unroll
                for (int c = 0; c < 8; ++c)
                    acc[r][c] = fmaf(ra[r], rb[c], acc[r][c]);
        }
        __syncthreads();
    }
    #pragma unroll
    for (int r = 0; r < 4; ++r) {
        float* cp = Cq + (size_t)(m0 + rowb + r) * ND + colb;
        float4 o0 = {acc[r][0], acc[r][1], acc[r][2], acc[r][3]};
        float4 o1 = {acc[r][4], acc[r][5], acc[r][6], acc[r][7]};
        *(float4*)cp = o0;
        *(float4*)(cp + 4) = o1;
    }
}

// ---------------------------------------------------------------------------
// Kernel 2: q_norms. One wave (64 lanes) per row of 128; butterfly reduce.
// ---------------------------------------------------------------------------
__global__ __launch_bounds__(256) void qnorm_kernel(
    const float* __restrict__ q, float* __restrict__ qn)
{
    const int w = (blockIdx.x * 256 + threadIdx.x) >> 6;  // row 0..16383
    const int lane = threadIdx.x & 63;
    const float* r = q + (size_t)w * ND;
    float a = r[lane], b = r[lane + 64];
    float s = a * a + b * b;
    #pragma unroll
    for (int off = 32; off > 0; off >>= 1) s += __shfl_xor(s, off);
    if (lane == 0) qn[w] = sqrtf(s);
}

// ---------------------------------------------------------------------------
// Kernel 3: exact top-k by rank counting (matches jax.lax.top_k tie rules).
// rank_i = #{j : v_j > v_i  or (v_j == v_i and j < i)}; keep rank < 409.
// Compacted via atomic (set order irrelevant: output is a scatter).
// ---------------------------------------------------------------------------
__global__ __launch_bounds__(256) void topk_kernel(
    const float* __restrict__ qn, int* __restrict__ topi, int* __restrict__ cnt)
{
    __shared__ float vs[256];
    const int b = blockIdx.y;
    const int i = blockIdx.x * 256 + threadIdx.x;
    const float vi = qn[(size_t)b * NT + i];
    int rank = 0;
    for (int j0 = 0; j0 < NT; j0 += 256) {
        vs[threadIdx.x] = qn[(size_t)b * NT + j0 + threadIdx.x];
        __syncthreads();
        #pragma unroll 8
        for (int jj = 0; jj < 256; ++jj) {
            float vj = vs[jj];
            int j = j0 + jj;
            rank += (vj > vi || (vj == vi && j < i)) ? 1 : 0;
        }
        __syncthreads();
    }
    if (rank < NK) {
        int p = atomicAdd(&cnt[b], 1);
        topi[b * KPAD + p] = i;
    }
}

// ---------------------------------------------------------------------------
// Kernel 4: k_topk / v_topk only at the 1636 selected rows (vs 16384 dense:
// saves 10x of the K/V projection FLOPs).
// 4 gathered rows per block in LDS; thread t<128 -> Wk col t, t>=128 -> Wv.
// ---------------------------------------------------------------------------
__global__ __launch_bounds__(256) void kvproj_kernel(
    const float* __restrict__ X, const float* __restrict__ Wk,
    const float* __restrict__ Wv, const int* __restrict__ topi,
    float* __restrict__ ktop, float* __restrict__ vtop)
{
    __shared__ float As[4][NC];   // 32 KB
    const int t = threadIdx.x;
    const int g0 = blockIdx.x * 4;          // 1636 = 4*409 exact
    #pragma unroll
    for (int r = 0; r < 4; ++r) {
        int gi = g0 + r;
        int b = gi / NK, ii = gi % NK;
        int row = topi[b * KPAD + ii];
        const float* ap = X + ((size_t)(b * NT + row)) * NC;
        int e = t * 8;
        float4 u0 = *(const float4*)(ap + e);
        float4 u1 = *(const float4*)(ap + e + 4);
        As[r][e + 0] = u0.x; As[r][e + 1] = u0.y;
        As[r][e + 2] = u0.z; As[r][e + 3] = u0.w;
        As[r][e + 4] = u1.x; As[r][e + 5] = u1.y;
        As[r][e + 6] = u1.z; As[r][e + 7] = u1.w;
    }
    __syncthreads();
    const float* W = (t < ND) ? Wk : Wv;
    const int col = t & (ND - 1);
    float acc0 = 0.f, acc1 = 0.f, acc2 = 0.f, acc3 = 0.f;
    #pragma unroll 4
    for (int kk = 0; kk < NC; ++kk) {
        float w = W[(size_t)kk * ND + col];
        acc0 = fmaf(As[0][kk], w, acc0);
        acc1 = fmaf(As[1][kk], w, acc1);
        acc2 = fmaf(As[2][kk], w, acc2);
        acc3 = fmaf(As[3][kk], w, acc3);
    }
    float accs[4] = {acc0, acc1, acc2, acc3};
    float* dst = (t < ND) ? ktop : vtop;
    #pragma unroll
    for (int r = 0; r < 4; ++r) {
        int gi = g0 + r;
        int b = gi / NK, ii = gi % NK;
        dst[((size_t)b * NK + ii) * ND + col] = accs[r];
    }
}

// ---------------------------------------------------------------------------
// Kernel 5: one block per (batch, top-k row i): scores -> softmax -> PV,
// scatter directly into zeroed output at top_idx row. fp32 math, fp32 store.
// ---------------------------------------------------------------------------
__global__ __launch_bounds__(256) void attn_kernel(
    const float* __restrict__ q, const float* __restrict__ ktop,
    const float* __restrict__ vtop, const int* __restrict__ topi,
    float* __restrict__ out)
{
    __shared__ float qs[ND];
    __shared__ float ss[KPAD];
    __shared__ float red[256];
    const int bi = blockIdx.x;
    const int b = bi / NK, i = bi % NK;
    const int t = threadIdx.x;
    const int row = topi[b * KPAD + i];
    if (t < ND) qs[t] = q[((size_t)b * NT + row) * ND + t];
    __syncthreads();

    const float scale = 0.08838834764831844f;   // 1/sqrt(128)
    float mymax = -1e30f;
    #pragma unroll
    for (int rep = 0; rep < 2; ++rep) {
        int j = t + rep * 256;
        if (j < NK) {
            const float4* kr = (const float4*)(ktop + ((size_t)b * NK + j) * ND);
            const float4* q4 = (const float4*)qs;
            float s = 0.f;
            #pragma unroll
            for (int dd = 0; dd < 32; ++dd) {
                float4 a = q4[dd], kv = kr[dd];
                s += a.x * kv.x + a.y * kv.y + a.z * kv.z + a.w * kv.w;
            }
            s *= scale;
            ss[j] = s;
            mymax = fmaxf(mymax, s);
        }
    }
    red[t] = mymax;
    __syncthreads();
    for (int off = 128; off > 0; off >>= 1) {
        if (t < off) red[t] = fmaxf(red[t], red[t + off]);
        __syncthreads();
    }
    const float mx = red[0];
    __syncthreads();

    float mysum = 0.f;
    #pragma unroll
    for (int rep = 0; rep < 2; ++rep) {
        int j = t + rep * 256;
        if (j < NK) {
            float p = __expf(ss[j] - mx);
            ss[j] = p;
            mysum += p;
        }
    }
    red[t] = mysum;
    __syncthreads();
    for (int off = 128; off > 0; off >>= 1) {
        if (t < off) red[t] += red[t + off];
        __syncthreads();
    }
    const float inv = 1.f / red[0];

    if (t < ND) {
        float o = 0.f;
        for (int j = 0; j < NK; ++j)
            o = fmaf(ss[j], vtop[((size_t)b * NK + j) * ND + t], o);
        out[((size_t)b * NT + row) * ND + t] = o * inv;
    }
}

// ---------------------------------------------------------------------------
extern "C" void kernel_launch(void* const* d_in, const int* in_sizes, int n_in,
                              void* d_out, int out_size, void* d_ws, size_t ws_size,
                              hipStream_t stream)
{
    const float* index = (const float*)d_in[0];
    const float* Wq = (const float*)d_in[1];
    const float* Wk = (const float*)d_in[2];
    const float* Wv = (const float*)d_in[3];
    float* out = (float*)d_out;

    // Workspace layout (~9.7 MB)
    char* ws = (char*)d_ws;
    float* q    = (float*)(ws);                                  // 8 MB
    float* qn   = (float*)(ws + 8388608);                        // 64 KB
    int*   topi = (int*)  (ws + 8388608 + 65536);                // 4*416*4
    int*   cnt  = (int*)  (ws + 8388608 + 65536 + 8192);         // 16 B
    float* ktop = (float*)(ws + 8388608 + 65536 + 8192 + 256);   // 818 KB
    float* vtop = ktop + (size_t)NB * NK * ND;                   // 818 KB

    hipMemsetAsync(cnt, 0, NB * sizeof(int), stream);
    hipMemsetAsync(d_out, 0, (size_t)out_size * sizeof(float), stream);

    qgemm_kernel<<<dim3(NB * NT / 64), dim3(256), 0, stream>>>(index, Wq, q);
    qnorm_kernel<<<dim3(NB * NT / 4), dim3(256), 0, stream>>>(q, qn);
    topk_kernel<<<dim3(NT / 256, NB), dim3(256), 0, stream>>>(qn, topi, cnt);
    kvproj_kernel<<<dim3(NB * NK / 4), dim3(256), 0, stream>>>(index, Wk, Wv, topi, ktop, vtop);
    attn_kernel<<<dim3(NB * NK), dim3(256), 0, stream>>>(q, ktop, vtop, topi, out);
}

// Round 5
// 608.436 us; speedup vs baseline: 1.2457x; 1.2457x over previous
//
#include <hip/hip_runtime.h>
#include <hip/hip_bf16.h>

// Problem constants (Head_24799141167224)
// Device buffers: inputs fp32, output fp32 (comparison at bf16 precision, 2% rel).
// ws_size evidence: 10,137,856 B (R3) ran; 11,186,432 B (R4) memory-faulted.
// => keep total workspace <= 10,137,856 B (alias Bhi/Blo with ktop/vtop).
#define NB 4
#define NT 4096
#define NC 2048
#define ND 128
#define NK 409      // int(0.1 * 4096)
#define KPAD 416

#define BM 32
#define BK 32
#define ASTR 40     // padded LDS row stride (ushorts) for A tiles

typedef __attribute__((ext_vector_type(8))) short short8;   // 8 bf16 (4 VGPRs)
typedef __attribute__((ext_vector_type(4))) float f32x4;

// RNE split: x = hi + lo (both bf16), |x - hi - lo| <= ~2^-18 |x|
__device__ __forceinline__ void split2(float x, ushort& h, ushort& l) {
    union { float f; unsigned u; } a; a.f = x;
    unsigned r = a.u + 0x7FFFu + ((a.u >> 16) & 1u);
    h = (ushort)(r >> 16);
    union { unsigned u; float f; } hb; hb.u = ((unsigned)h) << 16;
    float res = x - hb.f;                       // exact (Sterbenz-close)
    union { float f; unsigned u; } b; b.f = res;
    unsigned r2 = b.u + 0x7FFFu + ((b.u >> 16) & 1u);
    l = (ushort)(r2 >> 16);
}

__device__ __forceinline__ uint2 pack4(const ushort* s) {
    uint2 v;
    v.x = (unsigned)s[0] | ((unsigned)s[1] << 16);
    v.y = (unsigned)s[2] | ((unsigned)s[3] << 16);
    return v;
}

__device__ __forceinline__ uint4 pack8(const ushort* s) {
    uint4 v;
    v.x = (unsigned)s[0] | ((unsigned)s[1] << 16);
    v.y = (unsigned)s[2] | ((unsigned)s[3] << 16);
    v.z = (unsigned)s[4] | ((unsigned)s[5] << 16);
    v.w = (unsigned)s[6] | ((unsigned)s[7] << 16);
    return v;
}

// ---------------------------------------------------------------------------
// Kernel 0: Wq [2048][128] fp32 -> Bhi/Blo [128][2048] bf16 (transposed,
// MFMA-B-friendly: 8 contiguous k per 16B). 64 blocks x 256 thr.
// ---------------------------------------------------------------------------
__global__ __launch_bounds__(256) void bconv_kernel(
    const float* __restrict__ Wq, ushort* __restrict__ Bhi, ushort* __restrict__ Blo)
{
    const int t = threadIdx.x;
    const int n = t & 127;
    const int kk0 = blockIdx.x * 32 + (t >> 7) * 16;
    ushort hb[16], lb[16];
    #pragma unroll
    for (int j = 0; j < 16; ++j) {
        float x = Wq[(size_t)(kk0 + j) * ND + n];   // coalesced over n
        split2(x, hb[j], lb[j]);
    }
    *(uint4*)&Bhi[(size_t)n * NC + kk0 + 0] = pack8(hb);
    *(uint4*)&Bhi[(size_t)n * NC + kk0 + 8] = pack8(hb + 8);
    *(uint4*)&Blo[(size_t)n * NC + kk0 + 0] = pack8(lb);
    *(uint4*)&Blo[(size_t)n * NC + kk0 + 8] = pack8(lb + 8);
}

// ---------------------------------------------------------------------------
// Kernel 1: q = index @ Wq via split-bf16 MFMA (hi*hi + hi*lo + lo*hi),
// fp32 accumulate. BM=32 x BN=128(full), BK=32 -> 512 blocks (2/CU), direct
// stores (no split-K, no atomics). A read once from HBM (128 MB ~ 21 us floor).
// q error ~4e-6 << ~1e-3 order-stat gap at rank 409 -> exact top-k set.
// ---------------------------------------------------------------------------
__global__ __launch_bounds__(256, 2) void qgemm_mfma(
    const float* __restrict__ A, const ushort* __restrict__ Bhi,
    const ushort* __restrict__ Blo, float* __restrict__ q)
{
    __shared__ ushort Ah[BM * ASTR];    // 2560 B
    __shared__ ushort Al[BM * ASTR];
    __shared__ ushort Bh[128 * BK];     // 8 KB, [n][k]
    __shared__ ushort Bl[128 * BK];

    const int tid  = threadIdx.x;
    const int m0   = blockIdx.x * BM;
    const int w    = tid >> 6;          // wave 0..3
    const int lane = tid & 63;
    const int wm   = w >> 1, wn = w & 1;   // 16-row group / 64-col group
    const int lrow = lane & 15, lq = lane >> 4;

    // A staging: thread t -> row t>>3 (0..31), k (t&7)*4   (1 float4)
    const int ar = tid >> 3, ak = (tid & 7) * 4;
    const float* aptr = A + (size_t)(m0 + ar) * NC + ak;
    // B staging: thread t -> n t>>1 (0..127), k (t&1)*16   (2 uint4 per half)
    const int br = tid >> 1, bk = (tid & 1) * 16;
    const ushort* bhp = Bhi + (size_t)br * NC + bk;
    const ushort* blp = Blo + (size_t)br * NC + bk;

    f32x4 acc[4];
    #pragma unroll
    for (int j = 0; j < 4; ++j) acc[j] = (f32x4){0.f, 0.f, 0.f, 0.f};

    for (int k0 = 0; k0 < NC; k0 += BK) {
        float4 f0 = *(const float4*)(aptr + k0);
        uint4 bh0 = *(const uint4*)(bhp + k0);
        uint4 bh1 = *(const uint4*)(bhp + k0 + 8);
        uint4 bl0 = *(const uint4*)(blp + k0);
        uint4 bl1 = *(const uint4*)(blp + k0 + 8);
        ushort h[4], l[4];
        split2(f0.x, h[0], l[0]);
        split2(f0.y, h[1], l[1]);
        split2(f0.z, h[2], l[2]);
        split2(f0.w, h[3], l[3]);

        __syncthreads();   // previous tile's fragment reads done
        *(uint2*)&Ah[ar * ASTR + ak] = pack4(h);
        *(uint2*)&Al[ar * ASTR + ak] = pack4(l);
        *(uint4*)&Bh[br * BK + bk + 0] = bh0;
        *(uint4*)&Bh[br * BK + bk + 8] = bh1;
        *(uint4*)&Bl[br * BK + bk + 0] = bl0;
        *(uint4*)&Bl[br * BK + bk + 8] = bl1;
        __syncthreads();

        const int row = wm * 16 + lrow;
        short8 ah = *(const short8*)&Ah[row * ASTR + lq * 8];
        short8 al = *(const short8*)&Al[row * ASTR + lq * 8];
        #pragma unroll
        for (int ni = 0; ni < 4; ++ni) {
            const int n = wn * 64 + ni * 16 + lrow;
            short8 bhf = *(const short8*)&Bh[n * BK + lq * 8];
            short8 blf = *(const short8*)&Bl[n * BK + lq * 8];
            acc[ni] = __builtin_amdgcn_mfma_f32_16x16x32_bf16(ah, bhf, acc[ni], 0, 0, 0);
            acc[ni] = __builtin_amdgcn_mfma_f32_16x16x32_bf16(ah, blf, acc[ni], 0, 0, 0);
            acc[ni] = __builtin_amdgcn_mfma_f32_16x16x32_bf16(al, bhf, acc[ni], 0, 0, 0);
        }
    }

    // C/D layout: col = lane&15, row = lq*4 + r
    #pragma unroll
    for (int ni = 0; ni < 4; ++ni) {
        const int col = wn * 64 + ni * 16 + lrow;
        #pragma unroll
        for (int r = 0; r < 4; ++r) {
            const int grow = m0 + wm * 16 + lq * 4 + r;
            q[(size_t)grow * ND + col] = acc[ni][r];
        }
    }
}

// ---------------------------------------------------------------------------
// Kernel 2: q_norms. One wave per row of 128; butterfly reduce.
// ---------------------------------------------------------------------------
__global__ __launch_bounds__(256) void qnorm_kernel(
    const float* __restrict__ q, float* __restrict__ qn)
{
    const int wv = (blockIdx.x * 256 + threadIdx.x) >> 6;
    const int lane = threadIdx.x & 63;
    const float* r = q + (size_t)wv * ND;
    float a = r[lane], b = r[lane + 64];
    float s = a * a + b * b;
    #pragma unroll
    for (int off = 32; off > 0; off >>= 1) s += __shfl_xor(s, off);
    if (lane == 0) qn[wv] = sqrtf(s);
}

// ---------------------------------------------------------------------------
// Kernel 3: exact top-k by rank counting, 4-way j-split per i.
// grid (NT/64, NB) = 256 blocks; thread (i-sub, chunk); LDS reduce.
// ---------------------------------------------------------------------------
__global__ __launch_bounds__(256) void topk_kernel(
    const float* __restrict__ qn, int* __restrict__ topi, int* __restrict__ cnt)
{
    __shared__ int rs[4][64];
    const int b = blockIdx.y;
    const int is = threadIdx.x & 63;
    const int i = blockIdx.x * 64 + is;
    const int chunk = threadIdx.x >> 6;
    const float vi = qn[(size_t)b * NT + i];
    const float4* qv = (const float4*)(qn + (size_t)b * NT + chunk * 1024);
    int rank = 0;
    #pragma unroll 4
    for (int j4 = 0; j4 < 256; ++j4) {
        float4 v = qv[j4];
        int j = chunk * 1024 + j4 * 4;
        rank += (v.x > vi || (v.x == vi && (j + 0) < i)) ? 1 : 0;
        rank += (v.y > vi || (v.y == vi && (j + 1) < i)) ? 1 : 0;
        rank += (v.z > vi || (v.z == vi && (j + 2) < i)) ? 1 : 0;
        rank += (v.w > vi || (v.w == vi && (j + 3) < i)) ? 1 : 0;
    }
    rs[chunk][is] = rank;
    __syncthreads();
    if (threadIdx.x < 64) {
        int rk = rs[0][threadIdx.x] + rs[1][threadIdx.x] + rs[2][threadIdx.x] + rs[3][threadIdx.x];
        if (rk < NK) {
            int p = atomicAdd(&cnt[b], 1);
            topi[b * KPAD + p] = blockIdx.x * 64 + threadIdx.x;
        }
    }
}

// ---------------------------------------------------------------------------
// Kernel 4: k_topk/v_topk at the 1636 selected rows. 8 rows/block (205
// blocks); X-row loads broadcast (block-uniform); 8-way FMA ILP per W load.
// ---------------------------------------------------------------------------
__global__ __launch_bounds__(256) void kvproj_kernel(
    const float* __restrict__ X, const float* __restrict__ Wk,
    const float* __restrict__ Wv, const int* __restrict__ topi,
    float* __restrict__ ktop, float* __restrict__ vtop)
{
    const int t = threadIdx.x;
    const int g0 = blockIdx.x * 8;
    const float* __restrict__ W = (t < ND) ? Wk : Wv;
    const int col = t & (ND - 1);
    const float* xr[8];
    int dsti[8];
    #pragma unroll
    for (int r = 0; r < 8; ++r) {
        int gi = g0 + r;
        int valid = (gi < NB * NK);
        int gic = valid ? gi : 0;
        int b = gic / NK, ii = gic % NK;
        int row = topi[b * KPAD + ii];
        xr[r] = X + ((size_t)b * NT + row) * NC;
        dsti[r] = valid ? (b * NK + ii) : -1;
    }
    float acc[8];
    #pragma unroll
    for (int r = 0; r < 8; ++r) acc[r] = 0.f;
    #pragma unroll 2
    for (int k = 0; k < NC; k += 2) {
        float w0 = W[(size_t)k * ND + col];
        float w1 = W[(size_t)(k + 1) * ND + col];
        #pragma unroll
        for (int r = 0; r < 8; ++r) {
            acc[r] = fmaf(xr[r][k], w0, acc[r]);
            acc[r] = fmaf(xr[r][k + 1], w1, acc[r]);
        }
    }
    float* dst = (t < ND) ? ktop : vtop;
    #pragma unroll
    for (int r = 0; r < 8; ++r)
        if (dsti[r] >= 0) dst[(size_t)dsti[r] * ND + col] = acc[r];
}

// ---------------------------------------------------------------------------
// Kernel 5: per (batch, top-k row): scores -> softmax -> PV -> scatter.
// PV uses all 256 threads (j parity split) + partial combine in LDS.
// ---------------------------------------------------------------------------
__global__ __launch_bounds__(256) void attn_kernel(
    const float* __restrict__ q, const float* __restrict__ ktop,
    const float* __restrict__ vtop, const int* __restrict__ topi,
    float* __restrict__ out)
{
    __shared__ float qs[ND];
    __shared__ float ss[KPAD];
    __shared__ float red[256];
    __shared__ float pv[2][ND];
    const int bi = blockIdx.x;
    const int b = bi / NK, i = bi % NK;
    const int t = threadIdx.x;
    const int row = topi[b * KPAD + i];
    if (t < ND) qs[t] = q[((size_t)b * NT + row) * ND + t];
    __syncthreads();

    const float scale = 0.08838834764831844f;   // 1/sqrt(128)
    float mymax = -1e30f;
    #pragma unroll
    for (int rep = 0; rep < 2; ++rep) {
        int j = t + rep * 256;
        if (j < NK) {
            const float4* kr = (const float4*)(ktop + ((size_t)b * NK + j) * ND);
            const float4* q4 = (const float4*)qs;
            float s = 0.f;
            #pragma unroll
            for (int dd = 0; dd < 32; ++dd) {
                float4 a = q4[dd], kv = kr[dd];
                s += a.x * kv.x + a.y * kv.y + a.z * kv.z + a.w * kv.w;
            }
            s *= scale;
            ss[j] = s;
            mymax = fmaxf(mymax, s);
        }
    }
    red[t] = mymax;
    __syncthreads();
    for (int off = 128; off > 0; off >>= 1) {
        if (t < off) red[t] = fmaxf(red[t], red[t + off]);
        __syncthreads();
    }
    const float mx = red[0];
    __syncthreads();

    float mysum = 0.f;
    #pragma unroll
    for (int rep = 0; rep < 2; ++rep) {
        int j = t + rep * 256;
        if (j < NK) {
            float p = __expf(ss[j] - mx);
            ss[j] = p;
            mysum += p;
        }
    }
    red[t] = mysum;
    __syncthreads();
    for (int off = 128; off > 0; off >>= 1) {
        if (t < off) red[t] += red[t + off];
        __syncthreads();
    }
    const float inv = 1.f / red[0];

    // PV: all 256 threads, parity split over j
    const int col = t & (ND - 1), half = t >> 7;
    float o = 0.f;
    #pragma unroll 4
    for (int j = half; j < NK; j += 2)
        o = fmaf(ss[j], vtop[((size_t)b * NK + j) * ND + col], o);
    pv[half][col] = o;
    __syncthreads();
    if (t < ND)
        out[((size_t)b * NT + row) * ND + t] = (pv[0][t] + pv[1][t]) * inv;
}

// ---------------------------------------------------------------------------
extern "C" void kernel_launch(void* const* d_in, const int* in_sizes, int n_in,
                              void* d_out, int out_size, void* d_ws, size_t ws_size,
                              hipStream_t stream)
{
    const float* index = (const float*)d_in[0];
    const float* Wq = (const float*)d_in[1];
    const float* Wk = (const float*)d_in[2];
    const float* Wv = (const float*)d_in[3];
    float* out = (float*)d_out;

    // Workspace layout: total 10,137,856 B == R3-proven footprint.
    // Bhi/Blo alias ktop/vtop: Bhi/Blo die after qgemm_mfma; ktop/vtop are
    // first written by kvproj_kernel, which is stream-ordered after it.
    char* ws = (char*)d_ws;
    float*  q    = (float*)(ws);                       // 8,388,608
    float*  qn   = (float*)(ws + 8388608);             //    65,536
    int*    topi = (int*)  (ws + 8454144);             //     8,192
    int*    cnt  = (int*)  (ws + 8462336);             //       256
    float*  ktop = (float*)(ws + 8462592);             //   837,632
    float*  vtop = (float*)(ws + 9300224);             //   837,632
    ushort* Bhi  = (ushort*)(ws + 8462592);            //   524,288 (alias)
    ushort* Blo  = (ushort*)(ws + 8986880);            //   524,288 (alias)

    hipMemsetAsync(cnt, 0, NB * sizeof(int), stream);
    hipMemsetAsync(d_out, 0, (size_t)out_size * sizeof(float), stream);

    bconv_kernel<<<dim3(NC / 32), dim3(256), 0, stream>>>(Wq, Bhi, Blo);
    qgemm_mfma<<<dim3(NB * NT / BM), dim3(256), 0, stream>>>(index, Bhi, Blo, q);
    qnorm_kernel<<<dim3(NB * NT / 4), dim3(256), 0, stream>>>(q, qn);
    topk_kernel<<<dim3(NT / 64, NB), dim3(256), 0, stream>>>(qn, topi, cnt);
    kvproj_kernel<<<dim3((NB * NK + 7) / 8), dim3(256), 0, stream>>>(index, Wk, Wv, topi, ktop, vtop);
    attn_kernel<<<dim3(NB * NK), dim3(256), 0, stream>>>(q, ktop, vtop, topi, out);
}

// Round 6
// 413.460 us; speedup vs baseline: 1.8331x; 1.4716x over previous
//
#include <hip/hip_runtime.h>
#include <hip/hip_bf16.h>

// Problem constants (Head_24799141167224)
// Device buffers: inputs fp32, output fp32 (comparison at bf16 precision, 2% rel).
// ws_size evidence: 10,137,856 B (R3/R5) runs; 11,186,432 B (R4) faulted.
// => workspace capped at 10,137,856 B; d_out (8 MB) doubles as scratch for
//    the bf16 weight buffers until attn_kernel (stream-ordered, then memset 0).
#define NB 4
#define NT 4096
#define NC 2048
#define ND 128
#define NK 409      // int(0.1 * 4096)
#define KPAD 416

#define BM 32
#define BK 32
#define ASTR 40     // padded LDS row stride (ushorts): 2-way banks (free, m136)
#define BSTR 40

typedef __attribute__((ext_vector_type(8))) short short8;   // 8 bf16 (4 VGPRs)
typedef __attribute__((ext_vector_type(4))) float f32x4;

// RNE split: x = hi + lo (both bf16), |x - hi - lo| <= ~2^-18 |x|
__device__ __forceinline__ void split2(float x, ushort& h, ushort& l) {
    union { float f; unsigned u; } a; a.f = x;
    unsigned r = a.u + 0x7FFFu + ((a.u >> 16) & 1u);
    h = (ushort)(r >> 16);
    union { unsigned u; float f; } hb; hb.u = ((unsigned)h) << 16;
    float res = x - hb.f;
    union { float f; unsigned u; } b; b.f = res;
    unsigned r2 = b.u + 0x7FFFu + ((b.u >> 16) & 1u);
    l = (ushort)(r2 >> 16);
}

__device__ __forceinline__ uint2 pack4(const ushort* s) {
    uint2 v;
    v.x = (unsigned)s[0] | ((unsigned)s[1] << 16);
    v.y = (unsigned)s[2] | ((unsigned)s[3] << 16);
    return v;
}

__device__ __forceinline__ uint4 pack8(const ushort* s) {
    uint4 v;
    v.x = (unsigned)s[0] | ((unsigned)s[1] << 16);
    v.y = (unsigned)s[2] | ((unsigned)s[3] << 16);
    v.z = (unsigned)s[4] | ((unsigned)s[5] << 16);
    v.w = (unsigned)s[6] | ((unsigned)s[7] << 16);
    return v;
}

// ---------------------------------------------------------------------------
// Kernel 0a: Wq [2048][128] fp32 -> Bhi/Blo [128][2048] bf16 (transposed).
// ---------------------------------------------------------------------------
__global__ __launch_bounds__(256) void bconv_kernel(
    const float* __restrict__ Wq, ushort* __restrict__ Bhi, ushort* __restrict__ Blo)
{
    const int t = threadIdx.x;
    const int n = t & 127;
    const int kk0 = blockIdx.x * 32 + (t >> 7) * 16;
    ushort hb[16], lb[16];
    #pragma unroll
    for (int j = 0; j < 16; ++j) {
        float x = Wq[(size_t)(kk0 + j) * ND + n];   // coalesced over n
        split2(x, hb[j], lb[j]);
    }
    *(uint4*)&Bhi[(size_t)n * NC + kk0 + 0] = pack8(hb);
    *(uint4*)&Bhi[(size_t)n * NC + kk0 + 8] = pack8(hb + 8);
    *(uint4*)&Blo[(size_t)n * NC + kk0 + 0] = pack8(lb);
    *(uint4*)&Blo[(size_t)n * NC + kk0 + 8] = pack8(lb + 8);
}

// ---------------------------------------------------------------------------
// Kernel 0b: Wk,Wv -> Bkv hi/lo [256][2048] bf16 (rows 0..127 = Wk cols,
// rows 128..255 = Wv cols). grid (64, 2).
// ---------------------------------------------------------------------------
__global__ __launch_bounds__(256) void bconv_kv_kernel(
    const float* __restrict__ Wk, const float* __restrict__ Wv,
    ushort* __restrict__ Bhi, ushort* __restrict__ Blo)
{
    const float* __restrict__ W = blockIdx.y ? Wv : Wk;
    const int t = threadIdx.x;
    const int n = t & 127;
    const int nr = blockIdx.y * 128 + n;
    const int kk0 = blockIdx.x * 32 + (t >> 7) * 16;
    ushort hb[16], lb[16];
    #pragma unroll
    for (int j = 0; j < 16; ++j) {
        float x = W[(size_t)(kk0 + j) * ND + n];
        split2(x, hb[j], lb[j]);
    }
    *(uint4*)&Bhi[(size_t)nr * NC + kk0 + 0] = pack8(hb);
    *(uint4*)&Bhi[(size_t)nr * NC + kk0 + 8] = pack8(hb + 8);
    *(uint4*)&Blo[(size_t)nr * NC + kk0 + 0] = pack8(lb);
    *(uint4*)&Blo[(size_t)nr * NC + kk0 + 8] = pack8(lb + 8);
}

// ---------------------------------------------------------------------------
// Kernel 1: q = index @ Wq via split-bf16 MFMA (hi*hi + hi*lo + lo*hi),
// fp32 accumulate. BM=32 x BN=128(full), BK=32 -> 512 blocks, direct stores.
// q error ~4e-6 << ~1e-3 order-stat gap at rank 409 -> exact top-k set.
// ---------------------------------------------------------------------------
__global__ __launch_bounds__(256, 2) void qgemm_mfma(
    const float* __restrict__ A, const ushort* __restrict__ Bhi,
    const ushort* __restrict__ Blo, float* __restrict__ q)
{
    __shared__ ushort Ah[BM * ASTR];
    __shared__ ushort Al[BM * ASTR];
    __shared__ ushort Bh[128 * BSTR];
    __shared__ ushort Bl[128 * BSTR];

    const int tid  = threadIdx.x;
    const int m0   = blockIdx.x * BM;
    const int w    = tid >> 6;
    const int lane = tid & 63;
    const int wm   = w >> 1, wn = w & 1;
    const int lrow = lane & 15, lq = lane >> 4;

    const int ar = tid >> 3, ak = (tid & 7) * 4;
    const float* aptr = A + (size_t)(m0 + ar) * NC + ak;
    const int br = tid >> 1, bk = (tid & 1) * 16;
    const ushort* bhp = Bhi + (size_t)br * NC + bk;
    const ushort* blp = Blo + (size_t)br * NC + bk;

    f32x4 acc[4];
    #pragma unroll
    for (int j = 0; j < 4; ++j) acc[j] = (f32x4){0.f, 0.f, 0.f, 0.f};

    for (int k0 = 0; k0 < NC; k0 += BK) {
        float4 f0 = *(const float4*)(aptr + k0);
        uint4 bh0 = *(const uint4*)(bhp + k0);
        uint4 bh1 = *(const uint4*)(bhp + k0 + 8);
        uint4 bl0 = *(const uint4*)(blp + k0);
        uint4 bl1 = *(const uint4*)(blp + k0 + 8);
        ushort h[4], l[4];
        split2(f0.x, h[0], l[0]);
        split2(f0.y, h[1], l[1]);
        split2(f0.z, h[2], l[2]);
        split2(f0.w, h[3], l[3]);

        __syncthreads();
        *(uint2*)&Ah[ar * ASTR + ak] = pack4(h);
        *(uint2*)&Al[ar * ASTR + ak] = pack4(l);
        *(uint4*)&Bh[br * BSTR + bk + 0] = bh0;
        *(uint4*)&Bh[br * BSTR + bk + 8] = bh1;
        *(uint4*)&Bl[br * BSTR + bk + 0] = bl0;
        *(uint4*)&Bl[br * BSTR + bk + 8] = bl1;
        __syncthreads();

        const int row = wm * 16 + lrow;
        short8 ah = *(const short8*)&Ah[row * ASTR + lq * 8];
        short8 al = *(const short8*)&Al[row * ASTR + lq * 8];
        #pragma unroll
        for (int ni = 0; ni < 4; ++ni) {
            const int n = wn * 64 + ni * 16 + lrow;
            short8 bhf = *(const short8*)&Bh[n * BSTR + lq * 8];
            short8 blf = *(const short8*)&Bl[n * BSTR + lq * 8];
            acc[ni] = __builtin_amdgcn_mfma_f32_16x16x32_bf16(ah, bhf, acc[ni], 0, 0, 0);
            acc[ni] = __builtin_amdgcn_mfma_f32_16x16x32_bf16(ah, blf, acc[ni], 0, 0, 0);
            acc[ni] = __builtin_amdgcn_mfma_f32_16x16x32_bf16(al, bhf, acc[ni], 0, 0, 0);
        }
    }

    // C/D layout: col = lane&15, row = lq*4 + r
    #pragma unroll
    for (int ni = 0; ni < 4; ++ni) {
        const int col = wn * 64 + ni * 16 + lrow;
        #pragma unroll
        for (int r = 0; r < 4; ++r) {
            const int grow = m0 + wm * 16 + lq * 4 + r;
            q[(size_t)grow * ND + col] = acc[ni][r];
        }
    }
}

// ---------------------------------------------------------------------------
// Kernel 1b: gathered K/V projection via split-bf16 MFMA.
// M = 1636 top-k rows (gathered through topi), N = 128 (K or V per
// blockIdx.y), K = 2048. Same tile structure as qgemm_mfma.
// ---------------------------------------------------------------------------
__global__ __launch_bounds__(256, 2) void kvgemm_mfma(
    const float* __restrict__ X, const ushort* __restrict__ Bhi,
    const ushort* __restrict__ Blo, const int* __restrict__ topi,
    float* __restrict__ ktop, float* __restrict__ vtop)
{
    __shared__ ushort Ah[BM * ASTR];
    __shared__ ushort Al[BM * ASTR];
    __shared__ ushort Bh[128 * BSTR];
    __shared__ ushort Bl[128 * BSTR];

    const int tid  = threadIdx.x;
    const int m0   = blockIdx.x * BM;
    const int w    = tid >> 6;
    const int lane = tid & 63;
    const int wm   = w >> 1, wn = w & 1;
    const int lrow = lane & 15, lq = lane >> 4;

    // A gather: compacted index gi -> (b, ii) -> source row
    const int ar = tid >> 3, ak = (tid & 7) * 4;
    int gi = m0 + ar;
    int giC = gi < NB * NK ? gi : NB * NK - 1;
    int b = giC / NK, ii = giC % NK;
    int srow = topi[b * KPAD + ii];
    const float* aptr = X + ((size_t)b * NT + srow) * NC + ak;

    const int br = tid >> 1, bk = (tid & 1) * 16;
    const ushort* bhp = Bhi + (size_t)(blockIdx.y * 128 + br) * NC + bk;
    const ushort* blp = Blo + (size_t)(blockIdx.y * 128 + br) * NC + bk;

    f32x4 acc[4];
    #pragma unroll
    for (int j = 0; j < 4; ++j) acc[j] = (f32x4){0.f, 0.f, 0.f, 0.f};

    for (int k0 = 0; k0 < NC; k0 += BK) {
        float4 f0 = *(const float4*)(aptr + k0);
        uint4 bh0 = *(const uint4*)(bhp + k0);
        uint4 bh1 = *(const uint4*)(bhp + k0 + 8);
        uint4 bl0 = *(const uint4*)(blp + k0);
        uint4 bl1 = *(const uint4*)(blp + k0 + 8);
        ushort h[4], l[4];
        split2(f0.x, h[0], l[0]);
        split2(f0.y, h[1], l[1]);
        split2(f0.z, h[2], l[2]);
        split2(f0.w, h[3], l[3]);

        __syncthreads();
        *(uint2*)&Ah[ar * ASTR + ak] = pack4(h);
        *(uint2*)&Al[ar * ASTR + ak] = pack4(l);
        *(uint4*)&Bh[br * BSTR + bk + 0] = bh0;
        *(uint4*)&Bh[br * BSTR + bk + 8] = bh1;
        *(uint4*)&Bl[br * BSTR + bk + 0] = bl0;
        *(uint4*)&Bl[br * BSTR + bk + 8] = bl1;
        __syncthreads();

        const int row = wm * 16 + lrow;
        short8 ah = *(const short8*)&Ah[row * ASTR + lq * 8];
        short8 al = *(const short8*)&Al[row * ASTR + lq * 8];
        #pragma unroll
        for (int ni = 0; ni < 4; ++ni) {
            const int n = wn * 64 + ni * 16 + lrow;
            short8 bhf = *(const short8*)&Bh[n * BSTR + lq * 8];
            short8 blf = *(const short8*)&Bl[n * BSTR + lq * 8];
            acc[ni] = __builtin_amdgcn_mfma_f32_16x16x32_bf16(ah, bhf, acc[ni], 0, 0, 0);
            acc[ni] = __builtin_amdgcn_mfma_f32_16x16x32_bf16(ah, blf, acc[ni], 0, 0, 0);
            acc[ni] = __builtin_amdgcn_mfma_f32_16x16x32_bf16(al, bhf, acc[ni], 0, 0, 0);
        }
    }

    float* __restrict__ dst = blockIdx.y ? vtop : ktop;
    #pragma unroll
    for (int ni = 0; ni < 4; ++ni) {
        const int col = wn * 64 + ni * 16 + lrow;
        #pragma unroll
        for (int r = 0; r < 4; ++r) {
            const int grow = m0 + wm * 16 + lq * 4 + r;   // compacted b*NK+ii
            if (grow < NB * NK)
                dst[(size_t)grow * ND + col] = acc[ni][r];
        }
    }
}

// ---------------------------------------------------------------------------
// Kernel 2: q_norms. One wave per row of 128; butterfly reduce.
// ---------------------------------------------------------------------------
__global__ __launch_bounds__(256) void qnorm_kernel(
    const float* __restrict__ q, float* __restrict__ qn)
{
    const int wv = (blockIdx.x * 256 + threadIdx.x) >> 6;
    const int lane = threadIdx.x & 63;
    const float* r = q + (size_t)wv * ND;
    float a = r[lane], b = r[lane + 64];
    float s = a * a + b * b;
    #pragma unroll
    for (int off = 32; off > 0; off >>= 1) s += __shfl_xor(s, off);
    if (lane == 0) qn[wv] = sqrtf(s);
}

// ---------------------------------------------------------------------------
// Kernel 3: exact top-k by rank counting (jax.lax.top_k tie rules).
// ---------------------------------------------------------------------------
__global__ __launch_bounds__(256) void topk_kernel(
    const float* __restrict__ qn, int* __restrict__ topi, int* __restrict__ cnt)
{
    __shared__ int rs[4][64];
    const int b = blockIdx.y;
    const int is = threadIdx.x & 63;
    const int i = blockIdx.x * 64 + is;
    const int chunk = threadIdx.x >> 6;
    const float vi = qn[(size_t)b * NT + i];
    const float4* qv = (const float4*)(qn + (size_t)b * NT + chunk * 1024);
    int rank = 0;
    #pragma unroll 4
    for (int j4 = 0; j4 < 256; ++j4) {
        float4 v = qv[j4];
        int j = chunk * 1024 + j4 * 4;
        rank += (v.x > vi || (v.x == vi && (j + 0) < i)) ? 1 : 0;
        rank += (v.y > vi || (v.y == vi && (j + 1) < i)) ? 1 : 0;
        rank += (v.z > vi || (v.z == vi && (j + 2) < i)) ? 1 : 0;
        rank += (v.w > vi || (v.w == vi && (j + 3) < i)) ? 1 : 0;
    }
    rs[chunk][is] = rank;
    __syncthreads();
    if (threadIdx.x < 64) {
        int rk = rs[0][threadIdx.x] + rs[1][threadIdx.x] + rs[2][threadIdx.x] + rs[3][threadIdx.x];
        if (rk < NK) {
            int p = atomicAdd(&cnt[b], 1);
            topi[b * KPAD + p] = blockIdx.x * 64 + threadIdx.x;
        }
    }
}

// ---------------------------------------------------------------------------
// Kernel 5: per (batch, top-k row): scores -> softmax -> PV -> scatter.
// ---------------------------------------------------------------------------
__global__ __launch_bounds__(256) void attn_kernel(
    const float* __restrict__ q, const float* __restrict__ ktop,
    const float* __restrict__ vtop, const int* __restrict__ topi,
    float* __restrict__ out)
{
    __shared__ float qs[ND];
    __shared__ float ss[KPAD];
    __shared__ float red[256];
    __shared__ float pv[2][ND];
    const int bi = blockIdx.x;
    const int b = bi / NK, i = bi % NK;
    const int t = threadIdx.x;
    const int row = topi[b * KPAD + i];
    if (t < ND) qs[t] = q[((size_t)b * NT + row) * ND + t];
    __syncthreads();

    const float scale = 0.08838834764831844f;   // 1/sqrt(128)
    float mymax = -1e30f;
    #pragma unroll
    for (int rep = 0; rep < 2; ++rep) {
        int j = t + rep * 256;
        if (j < NK) {
            const float4* kr = (const float4*)(ktop + ((size_t)b * NK + j) * ND);
            const float4* q4 = (const float4*)qs;
            float s = 0.f;
            #pragma unroll
            for (int dd = 0; dd < 32; ++dd) {
                float4 a = q4[dd], kv = kr[dd];
                s += a.x * kv.x + a.y * kv.y + a.z * kv.z + a.w * kv.w;
            }
            s *= scale;
            ss[j] = s;
            mymax = fmaxf(mymax, s);
        }
    }
    red[t] = mymax;
    __syncthreads();
    for (int off = 128; off > 0; off >>= 1) {
        if (t < off) red[t] = fmaxf(red[t], red[t + off]);
        __syncthreads();
    }
    const float mx = red[0];
    __syncthreads();

    float mysum = 0.f;
    #pragma unroll
    for (int rep = 0; rep < 2; ++rep) {
        int j = t + rep * 256;
        if (j < NK) {
            float p = __expf(ss[j] - mx);
            ss[j] = p;
            mysum += p;
        }
    }
    red[t] = mysum;
    __syncthreads();
    for (int off = 128; off > 0; off >>= 1) {
        if (t < off) red[t] += red[t + off];
        __syncthreads();
    }
    const float inv = 1.f / red[0];

    const int col = t & (ND - 1), half = t >> 7;
    float o = 0.f;
    #pragma unroll 4
    for (int j = half; j < NK; j += 2)
        o = fmaf(ss[j], vtop[((size_t)b * NK + j) * ND + col], o);
    pv[half][col] = o;
    __syncthreads();
    if (t < ND)
        out[((size_t)b * NT + row) * ND + t] = (pv[0][t] + pv[1][t]) * inv;
}

// ---------------------------------------------------------------------------
extern "C" void kernel_launch(void* const* d_in, const int* in_sizes, int n_in,
                              void* d_out, int out_size, void* d_ws, size_t ws_size,
                              hipStream_t stream)
{
    const float* index = (const float*)d_in[0];
    const float* Wq = (const float*)d_in[1];
    const float* Wk = (const float*)d_in[2];
    const float* Wv = (const float*)d_in[3];
    float* out = (float*)d_out;

    // Workspace: exactly the R3/R5-proven 10,137,856 B footprint.
    char* ws = (char*)d_ws;
    float*  q    = (float*)(ws);                       // 8,388,608
    float*  qn   = (float*)(ws + 8388608);             //    65,536
    int*    topi = (int*)  (ws + 8454144);             //     8,192
    int*    cnt  = (int*)  (ws + 8462336);             //       256
    float*  ktop = (float*)(ws + 8462592);             //   837,632
    float*  vtop = (float*)(ws + 9300224);             //   837,632

    // d_out (8,388,608 B) is scratch until attn_kernel:
    //   phase 1: Bq hi/lo (1 MB)  -- dead after qgemm_mfma
    //   phase 2: Bkv hi/lo (2 MB) -- dead after kvgemm_mfma
    // then memset 0 and attn scatters into it.
    ushort* Bqhi  = (ushort*)d_out;                    //   524,288
    ushort* Bqlo  = (ushort*)((char*)d_out + 524288);  //   524,288
    ushort* Bkvhi = (ushort*)d_out;                    // 1,048,576
    ushort* Bkvlo = (ushort*)((char*)d_out + 1048576); // 1,048,576

    hipMemsetAsync(cnt, 0, NB * sizeof(int), stream);

    bconv_kernel<<<dim3(NC / 32), dim3(256), 0, stream>>>(Wq, Bqhi, Bqlo);
    qgemm_mfma<<<dim3(NB * NT / BM), dim3(256), 0, stream>>>(index, Bqhi, Bqlo, q);
    qnorm_kernel<<<dim3(NB * NT / 4), dim3(256), 0, stream>>>(q, qn);
    topk_kernel<<<dim3(NT / 64, NB), dim3(256), 0, stream>>>(qn, topi, cnt);
    bconv_kv_kernel<<<dim3(NC / 32, 2), dim3(256), 0, stream>>>(Wk, Wv, Bkvhi, Bkvlo);
    kvgemm_mfma<<<dim3((NB * NK + BM - 1) / BM, 2), dim3(256), 0, stream>>>(
        index, Bkvhi, Bkvlo, topi, ktop, vtop);
    hipMemsetAsync(d_out, 0, (size_t)out_size * sizeof(float), stream);
    attn_kernel<<<dim3(NB * NK), dim3(256), 0, stream>>>(q, ktop, vtop, topi, out);
}

// Round 7
// 406.267 us; speedup vs baseline: 1.8655x; 1.0177x over previous
//
#include <hip/hip_runtime.h>
#include <hip/hip_bf16.h>

// Problem constants (Head_24799141167224)
// Device buffers: inputs fp32, output fp32 (comparison at bf16 precision, 2% rel).
// ws_size evidence: 10,137,856 B (R3/R5/R6) runs; 11,186,432 B (R4) faulted.
// d_out (8 MB) is scratch until attn: q2 split-K partial, then Bkv weights.
#define NB 4
#define NT 4096
#define NC 2048
#define ND 128
#define NK 409      // int(0.1 * 4096)
#define KPAD 416

#define BM 32
#define BK 32
#define ASTR 40     // padded LDS row stride (ushorts); row*80 B stays 16B-aligned
#define BSTR 40

typedef __attribute__((ext_vector_type(8))) short short8;   // 8 bf16 (4 VGPRs)
typedef __attribute__((ext_vector_type(4))) float f32x4;

// RNE split: x = hi + lo (both bf16), |x - hi - lo| <= ~2^-18 |x|
__device__ __forceinline__ void split2(float x, ushort& h, ushort& l) {
    union { float f; unsigned u; } a; a.f = x;
    unsigned r = a.u + 0x7FFFu + ((a.u >> 16) & 1u);
    h = (ushort)(r >> 16);
    union { unsigned u; float f; } hb; hb.u = ((unsigned)h) << 16;
    float res = x - hb.f;
    union { float f; unsigned u; } b; b.f = res;
    unsigned r2 = b.u + 0x7FFFu + ((b.u >> 16) & 1u);
    l = (ushort)(r2 >> 16);
}

__device__ __forceinline__ unsigned pack2(ushort a, ushort b) {
    return (unsigned)a | ((unsigned)b << 16);
}

__device__ __forceinline__ uint2 pack4(const ushort* s) {
    uint2 v;
    v.x = pack2(s[0], s[1]);
    v.y = pack2(s[2], s[3]);
    return v;
}

__device__ __forceinline__ uint4 pack8(const ushort* s) {
    uint4 v;
    v.x = pack2(s[0], s[1]);
    v.y = pack2(s[2], s[3]);
    v.z = pack2(s[4], s[5]);
    v.w = pack2(s[6], s[7]);
    return v;
}

// ---------------------------------------------------------------------------
// Kernel 0a: Wq [2048][128] fp32 -> Bhi/Blo [128][2048] bf16 (transposed).
// ---------------------------------------------------------------------------
__global__ __launch_bounds__(256) void bconv_kernel(
    const float* __restrict__ Wq, ushort* __restrict__ Bhi, ushort* __restrict__ Blo)
{
    const int t = threadIdx.x;
    const int n = t & 127;
    const int kk0 = blockIdx.x * 32 + (t >> 7) * 16;
    ushort hb[16], lb[16];
    #pragma unroll
    for (int j = 0; j < 16; ++j) {
        float x = Wq[(size_t)(kk0 + j) * ND + n];   // coalesced over n
        split2(x, hb[j], lb[j]);
    }
    *(uint4*)&Bhi[(size_t)n * NC + kk0 + 0] = pack8(hb);
    *(uint4*)&Bhi[(size_t)n * NC + kk0 + 8] = pack8(hb + 8);
    *(uint4*)&Blo[(size_t)n * NC + kk0 + 0] = pack8(lb);
    *(uint4*)&Blo[(size_t)n * NC + kk0 + 8] = pack8(lb + 8);
}

// ---------------------------------------------------------------------------
// Kernel 0b: Wk,Wv -> Bkv hi/lo [256][2048] bf16 (rows 0..127 = Wk cols,
// rows 128..255 = Wv cols). grid (64, 2).
// ---------------------------------------------------------------------------
__global__ __launch_bounds__(256) void bconv_kv_kernel(
    const float* __restrict__ Wk, const float* __restrict__ Wv,
    ushort* __restrict__ Bhi, ushort* __restrict__ Blo)
{
    const float* __restrict__ W = blockIdx.y ? Wv : Wk;
    const int t = threadIdx.x;
    const int n = t & 127;
    const int nr = blockIdx.y * 128 + n;
    const int kk0 = blockIdx.x * 32 + (t >> 7) * 16;
    ushort hb[16], lb[16];
    #pragma unroll
    for (int j = 0; j < 16; ++j) {
        float x = W[(size_t)(kk0 + j) * ND + n];
        split2(x, hb[j], lb[j]);
    }
    *(uint4*)&Bhi[(size_t)nr * NC + kk0 + 0] = pack8(hb);
    *(uint4*)&Bhi[(size_t)nr * NC + kk0 + 8] = pack8(hb + 8);
    *(uint4*)&Blo[(size_t)nr * NC + kk0 + 0] = pack8(lb);
    *(uint4*)&Blo[(size_t)nr * NC + kk0 + 8] = pack8(lb + 8);
}

// ---------------------------------------------------------------------------
// Kernel 1: q = index @ Wq via split-bf16 MFMA (hi*hi + hi*lo + lo*hi),
// fp32 accumulate. BM=32 x BN=128, BK=32, SPLIT-K=2 (blockIdx.y) -> 1024
// blocks = 4/CU. Register prefetch pipeline: next tile's global loads issue
// before the current tile's MFMA consume, hiding load latency.
// Partials: y=0 -> q1 (ws), y=1 -> q2 (d_out scratch); qnorm fuses the sum.
// ---------------------------------------------------------------------------
__global__ __launch_bounds__(256, 4) void qgemm_mfma(
    const float* __restrict__ A, const ushort* __restrict__ Bhi,
    const ushort* __restrict__ Blo, float* __restrict__ q1,
    float* __restrict__ q2)
{
    __shared__ ushort Ah[BM * ASTR];
    __shared__ ushort Al[BM * ASTR];
    __shared__ ushort Bh[128 * BSTR];
    __shared__ ushort Bl[128 * BSTR];

    const int tid  = threadIdx.x;
    const int m0   = blockIdx.x * BM;
    const int kb   = blockIdx.y * (NC / 2);   // split-K half
    const int w    = tid >> 6;
    const int lane = tid & 63;
    const int wm   = w >> 1, wn = w & 1;
    const int lrow = lane & 15, lq = lane >> 4;

    const int ar = tid >> 3, ak = (tid & 7) * 4;
    const float* aptr = A + (size_t)(m0 + ar) * NC + kb + ak;
    const int br = tid >> 1, bk = (tid & 1) * 16;
    const ushort* bhp = Bhi + (size_t)br * NC + kb + bk;
    const ushort* blp = Blo + (size_t)br * NC + kb + bk;

    f32x4 acc[4];
    #pragma unroll
    for (int j = 0; j < 4; ++j) acc[j] = (f32x4){0.f, 0.f, 0.f, 0.f};

    const int KITER = (NC / 2) / BK;   // 32
    // prologue: tile 0 loads
    float4 fA = *(const float4*)(aptr);
    uint4 vb0 = *(const uint4*)(bhp);
    uint4 vb1 = *(const uint4*)(bhp + 8);
    uint4 vb2 = *(const uint4*)(blp);
    uint4 vb3 = *(const uint4*)(blp + 8);

    for (int kt = 0; kt < KITER; ++kt) {
        ushort h[4], l[4];
        split2(fA.x, h[0], l[0]);
        split2(fA.y, h[1], l[1]);
        split2(fA.z, h[2], l[2]);
        split2(fA.w, h[3], l[3]);

        __syncthreads();   // previous tile's fragment reads done
        *(uint2*)&Ah[ar * ASTR + ak] = pack4(h);
        *(uint2*)&Al[ar * ASTR + ak] = pack4(l);
        *(uint4*)&Bh[br * BSTR + bk + 0] = vb0;
        *(uint4*)&Bh[br * BSTR + bk + 8] = vb1;
        *(uint4*)&Bl[br * BSTR + bk + 0] = vb2;
        *(uint4*)&Bl[br * BSTR + bk + 8] = vb3;
        __syncthreads();

        // prefetch next tile (in flight during ds_read + MFMA below)
        if (kt + 1 < KITER) {
            const int off = (kt + 1) * BK;
            fA  = *(const float4*)(aptr + off);
            vb0 = *(const uint4*)(bhp + off);
            vb1 = *(const uint4*)(bhp + off + 8);
            vb2 = *(const uint4*)(blp + off);
            vb3 = *(const uint4*)(blp + off + 8);
        }

        const int row = wm * 16 + lrow;
        short8 ah = *(const short8*)&Ah[row * ASTR + lq * 8];
        short8 al = *(const short8*)&Al[row * ASTR + lq * 8];
        #pragma unroll
        for (int ni = 0; ni < 4; ++ni) {
            const int n = wn * 64 + ni * 16 + lrow;
            short8 bhf = *(const short8*)&Bh[n * BSTR + lq * 8];
            short8 blf = *(const short8*)&Bl[n * BSTR + lq * 8];
            acc[ni] = __builtin_amdgcn_mfma_f32_16x16x32_bf16(ah, bhf, acc[ni], 0, 0, 0);
            acc[ni] = __builtin_amdgcn_mfma_f32_16x16x32_bf16(ah, blf, acc[ni], 0, 0, 0);
            acc[ni] = __builtin_amdgcn_mfma_f32_16x16x32_bf16(al, bhf, acc[ni], 0, 0, 0);
        }
    }

    float* __restrict__ qdst = blockIdx.y ? q2 : q1;
    // C/D layout: col = lane&15, row = lq*4 + r
    #pragma unroll
    for (int ni = 0; ni < 4; ++ni) {
        const int col = wn * 64 + ni * 16 + lrow;
        #pragma unroll
        for (int r = 0; r < 4; ++r) {
            const int grow = m0 + wm * 16 + lq * 4 + r;
            qdst[(size_t)grow * ND + col] = acc[ni][r];
        }
    }
}

// ---------------------------------------------------------------------------
// Kernel 1b: gathered K/V projection via split-bf16 MFMA. BM=16 -> grid
// (103, 2) = 206 blocks; register prefetch pipeline as in qgemm.
// ---------------------------------------------------------------------------
__global__ __launch_bounds__(256, 2) void kvgemm_mfma(
    const float* __restrict__ X, const ushort* __restrict__ Bhi,
    const ushort* __restrict__ Blo, const int* __restrict__ topi,
    float* __restrict__ ktop, float* __restrict__ vtop)
{
    __shared__ ushort Ah[16 * ASTR];
    __shared__ ushort Al[16 * ASTR];
    __shared__ ushort Bh[128 * BSTR];
    __shared__ ushort Bl[128 * BSTR];

    const int tid  = threadIdx.x;
    const int m0   = blockIdx.x * 16;
    const int w    = tid >> 6;
    const int lane = tid & 63;
    const int lrow = lane & 15, lq = lane >> 4;

    // A gather: compacted gi -> (b, ii) -> source row; clamp tail
    const int ar = tid >> 4, ak = (tid & 15) * 2;
    int gi = m0 + ar;
    int giC = gi < NB * NK ? gi : NB * NK - 1;
    int b = giC / NK, ii = giC % NK;
    int srow = topi[b * KPAD + ii];
    const float* aptr = X + ((size_t)b * NT + srow) * NC + ak;

    const int br = tid >> 1, bk = (tid & 1) * 16;
    const ushort* bhp = Bhi + (size_t)(blockIdx.y * 128 + br) * NC + bk;
    const ushort* blp = Blo + (size_t)(blockIdx.y * 128 + br) * NC + bk;

    f32x4 acc[2];
    acc[0] = (f32x4){0.f, 0.f, 0.f, 0.f};
    acc[1] = (f32x4){0.f, 0.f, 0.f, 0.f};

    const int KITER = NC / BK;   // 64
    float2 fA = *(const float2*)(aptr);
    uint4 vb0 = *(const uint4*)(bhp);
    uint4 vb1 = *(const uint4*)(bhp + 8);
    uint4 vb2 = *(const uint4*)(blp);
    uint4 vb3 = *(const uint4*)(blp + 8);

    for (int kt = 0; kt < KITER; ++kt) {
        ushort h[2], l[2];
        split2(fA.x, h[0], l[0]);
        split2(fA.y, h[1], l[1]);

        __syncthreads();
        *(unsigned*)&Ah[ar * ASTR + ak] = pack2(h[0], h[1]);
        *(unsigned*)&Al[ar * ASTR + ak] = pack2(l[0], l[1]);
        *(uint4*)&Bh[br * BSTR + bk + 0] = vb0;
        *(uint4*)&Bh[br * BSTR + bk + 8] = vb1;
        *(uint4*)&Bl[br * BSTR + bk + 0] = vb2;
        *(uint4*)&Bl[br * BSTR + bk + 8] = vb3;
        __syncthreads();

        if (kt + 1 < KITER) {
            const int off = (kt + 1) * BK;
            fA  = *(const float2*)(aptr + off);
            vb0 = *(const uint4*)(bhp + off);
            vb1 = *(const uint4*)(bhp + off + 8);
            vb2 = *(const uint4*)(blp + off);
            vb3 = *(const uint4*)(blp + off + 8);
        }

        short8 ah = *(const short8*)&Ah[lrow * ASTR + lq * 8];
        short8 al = *(const short8*)&Al[lrow * ASTR + lq * 8];
        #pragma unroll
        for (int ni = 0; ni < 2; ++ni) {
            const int n = w * 32 + ni * 16 + lrow;
            short8 bhf = *(const short8*)&Bh[n * BSTR + lq * 8];
            short8 blf = *(const short8*)&Bl[n * BSTR + lq * 8];
            acc[ni] = __builtin_amdgcn_mfma_f32_16x16x32_bf16(ah, bhf, acc[ni], 0, 0, 0);
            acc[ni] = __builtin_amdgcn_mfma_f32_16x16x32_bf16(ah, blf, acc[ni], 0, 0, 0);
            acc[ni] = __builtin_amdgcn_mfma_f32_16x16x32_bf16(al, bhf, acc[ni], 0, 0, 0);
        }
    }

    float* __restrict__ dst = blockIdx.y ? vtop : ktop;
    #pragma unroll
    for (int ni = 0; ni < 2; ++ni) {
        const int col = w * 32 + ni * 16 + lrow;
        #pragma unroll
        for (int r = 0; r < 4; ++r) {
            const int grow = m0 + lq * 4 + r;   // compacted b*NK+ii
            if (grow < NB * NK)
                dst[(size_t)grow * ND + col] = acc[ni][r];
        }
    }
}

// ---------------------------------------------------------------------------
// Kernel 2: q = q1 + q2 (in-place into q1) + q_norms. One wave per row.
// ---------------------------------------------------------------------------
__global__ __launch_bounds__(256) void qnorm_kernel(
    float* __restrict__ q1, const float* __restrict__ q2, float* __restrict__ qn)
{
    const int wv = (blockIdx.x * 256 + threadIdx.x) >> 6;
    const int lane = threadIdx.x & 63;
    float* r1 = q1 + (size_t)wv * ND;
    const float* r2 = q2 + (size_t)wv * ND;
    float a = r1[lane] + r2[lane];
    float b = r1[lane + 64] + r2[lane + 64];
    r1[lane] = a;
    r1[lane + 64] = b;
    float s = a * a + b * b;
    #pragma unroll
    for (int off = 32; off > 0; off >>= 1) s += __shfl_xor(s, off);
    if (lane == 0) qn[wv] = sqrtf(s);
}

// ---------------------------------------------------------------------------
// Kernel 3: exact top-k by rank counting (jax.lax.top_k tie rules).
// ---------------------------------------------------------------------------
__global__ __launch_bounds__(256) void topk_kernel(
    const float* __restrict__ qn, int* __restrict__ topi, int* __restrict__ cnt)
{
    __shared__ int rs[4][64];
    const int b = blockIdx.y;
    const int is = threadIdx.x & 63;
    const int i = blockIdx.x * 64 + is;
    const int chunk = threadIdx.x >> 6;
    const float vi = qn[(size_t)b * NT + i];
    const float4* qv = (const float4*)(qn + (size_t)b * NT + chunk * 1024);
    int rank = 0;
    #pragma unroll 4
    for (int j4 = 0; j4 < 256; ++j4) {
        float4 v = qv[j4];
        int j = chunk * 1024 + j4 * 4;
        rank += (v.x > vi || (v.x == vi && (j + 0) < i)) ? 1 : 0;
        rank += (v.y > vi || (v.y == vi && (j + 1) < i)) ? 1 : 0;
        rank += (v.z > vi || (v.z == vi && (j + 2) < i)) ? 1 : 0;
        rank += (v.w > vi || (v.w == vi && (j + 3) < i)) ? 1 : 0;
    }
    rs[chunk][is] = rank;
    __syncthreads();
    if (threadIdx.x < 64) {
        int rk = rs[0][threadIdx.x] + rs[1][threadIdx.x] + rs[2][threadIdx.x] + rs[3][threadIdx.x];
        if (rk < NK) {
            int p = atomicAdd(&cnt[b], 1);
            topi[b * KPAD + p] = blockIdx.x * 64 + threadIdx.x;
        }
    }
}

// ---------------------------------------------------------------------------
// Kernel 5: per (batch, top-k row): scores -> softmax -> PV -> scatter.
// ---------------------------------------------------------------------------
__global__ __launch_bounds__(256) void attn_kernel(
    const float* __restrict__ q, const float* __restrict__ ktop,
    const float* __restrict__ vtop, const int* __restrict__ topi,
    float* __restrict__ out)
{
    __shared__ float qs[ND];
    __shared__ float ss[KPAD];
    __shared__ float red[256];
    __shared__ float pv[2][ND];
    const int bi = blockIdx.x;
    const int b = bi / NK, i = bi % NK;
    const int t = threadIdx.x;
    const int row = topi[b * KPAD + i];
    if (t < ND) qs[t] = q[((size_t)b * NT + row) * ND + t];
    __syncthreads();

    const float scale = 0.08838834764831844f;   // 1/sqrt(128)
    float mymax = -1e30f;
    #pragma unroll
    for (int rep = 0; rep < 2; ++rep) {
        int j = t + rep * 256;
        if (j < NK) {
            const float4* kr = (const float4*)(ktop + ((size_t)b * NK + j) * ND);
            const float4* q4 = (const float4*)qs;
            float s = 0.f;
            #pragma unroll
            for (int dd = 0; dd < 32; ++dd) {
                float4 a = q4[dd], kv = kr[dd];
                s += a.x * kv.x + a.y * kv.y + a.z * kv.z + a.w * kv.w;
            }
            s *= scale;
            ss[j] = s;
            mymax = fmaxf(mymax, s);
        }
    }
    red[t] = mymax;
    __syncthreads();
    for (int off = 128; off > 0; off >>= 1) {
        if (t < off) red[t] = fmaxf(red[t], red[t + off]);
        __syncthreads();
    }
    const float mx = red[0];
    __syncthreads();

    float mysum = 0.f;
    #pragma unroll
    for (int rep = 0; rep < 2; ++rep) {
        int j = t + rep * 256;
        if (j < NK) {
            float p = __expf(ss[j] - mx);
            ss[j] = p;
            mysum += p;
        }
    }
    red[t] = mysum;
    __syncthreads();
    for (int off = 128; off > 0; off >>= 1) {
        if (t < off) red[t] += red[t + off];
        __syncthreads();
    }
    const float inv = 1.f / red[0];

    const int col = t & (ND - 1), half = t >> 7;
    float o = 0.f;
    #pragma unroll 4
    for (int j = half; j < NK; j += 2)
        o = fmaf(ss[j], vtop[((size_t)b * NK + j) * ND + col], o);
    pv[half][col] = o;
    __syncthreads();
    if (t < ND)
        out[((size_t)b * NT + row) * ND + t] = (pv[0][t] + pv[1][t]) * inv;
}

// ---------------------------------------------------------------------------
extern "C" void kernel_launch(void* const* d_in, const int* in_sizes, int n_in,
                              void* d_out, int out_size, void* d_ws, size_t ws_size,
                              hipStream_t stream)
{
    const float* index = (const float*)d_in[0];
    const float* Wq = (const float*)d_in[1];
    const float* Wk = (const float*)d_in[2];
    const float* Wv = (const float*)d_in[3];
    float* out = (float*)d_out;

    // Workspace: R3/R5/R6-proven 10,137,856 B footprint.
    // Tail region holds Bq (1 MB) during qgemm, then ktop/vtop (1.64 MB).
    char* ws = (char*)d_ws;
    float*  q1   = (float*)(ws);                       // 8,388,608
    float*  qn   = (float*)(ws + 8388608);             //    65,536
    int*    topi = (int*)  (ws + 8454144);             //     8,192
    int*    cnt  = (int*)  (ws + 8462336);             //       256
    ushort* Bqhi = (ushort*)(ws + 8462592);            //   524,288 (phase 1)
    ushort* Bqlo = (ushort*)(ws + 8986880);            //   524,288 (phase 1)
    float*  ktop = (float*)(ws + 8462592);             //   837,632 (phase 2)
    float*  vtop = (float*)(ws + 9300224);             //   837,632 (phase 2)

    // d_out (8 MB) scratch: q2 split-K partial, then Bkv hi/lo, then memset+attn.
    float*  q2    = (float*)d_out;
    ushort* Bkvhi = (ushort*)d_out;                    // 1,048,576
    ushort* Bkvlo = (ushort*)((char*)d_out + 1048576); // 1,048,576

    hipMemsetAsync(cnt, 0, NB * sizeof(int), stream);

    bconv_kernel<<<dim3(NC / 32), dim3(256), 0, stream>>>(Wq, Bqhi, Bqlo);
    qgemm_mfma<<<dim3(NB * NT / BM, 2), dim3(256), 0, stream>>>(index, Bqhi, Bqlo, q1, q2);
    qnorm_kernel<<<dim3(NB * NT / 4), dim3(256), 0, stream>>>(q1, q2, qn);
    topk_kernel<<<dim3(NT / 64, NB), dim3(256), 0, stream>>>(qn, topi, cnt);
    bconv_kv_kernel<<<dim3(NC / 32, 2), dim3(256), 0, stream>>>(Wk, Wv, Bkvhi, Bkvlo);
    kvgemm_mfma<<<dim3((NB * NK + 15) / 16, 2), dim3(256), 0, stream>>>(
        index, Bkvhi, Bkvlo, topi, ktop, vtop);
    hipMemsetAsync(d_out, 0, (size_t)out_size * sizeof(float), stream);
    attn_kernel<<<dim3(NB * NK), dim3(256), 0, stream>>>(q1, ktop, vtop, topi, out);
}

// Round 9
// 391.065 us; speedup vs baseline: 1.9381x; 1.0389x over previous
//
#include <hip/hip_runtime.h>
#include <hip/hip_bf16.h>

// Problem constants (Head_24799141167224)
// Inputs fp32, output fp32 (compared at bf16 precision, 2% rel).
// ws cap: 10,137,856 B proven (R4 fault at 11.2 MB). d_out = scratch until attn.
#define NB 4
#define NT 4096
#define NC 2048
#define ND 128
#define NK 409      // int(0.1 * 4096)
#define KPAD 416
#define NM (NB * NK)   // 1636

typedef __attribute__((ext_vector_type(8))) short short8;   // 8 bf16
typedef __attribute__((ext_vector_type(4))) float f32x4;

union S8U { short8 v; ushort u[8]; };

// RNE split: x = hi + lo (both bf16), |x - hi - lo| <= ~2^-18 |x|
__device__ __forceinline__ void split2(float x, ushort& h, ushort& l) {
    union { float f; unsigned u; } a; a.f = x;
    unsigned r = a.u + 0x7FFFu + ((a.u >> 16) & 1u);
    h = (ushort)(r >> 16);
    union { unsigned u; float f; } hb; hb.u = ((unsigned)h) << 16;
    float res = x - hb.f;
    union { float f; unsigned u; } b; b.f = res;
    unsigned r2 = b.u + 0x7FFFu + ((b.u >> 16) & 1u);
    l = (ushort)(r2 >> 16);
}

__device__ __forceinline__ uint4 pack8(const ushort* s) {
    uint4 v;
    v.x = (unsigned)s[0] | ((unsigned)s[1] << 16);
    v.y = (unsigned)s[2] | ((unsigned)s[3] << 16);
    v.z = (unsigned)s[4] | ((unsigned)s[5] << 16);
    v.w = (unsigned)s[6] | ((unsigned)s[7] << 16);
    return v;
}

// B tile-major slot with bank swizzle: 16 consecutive n at fixed lq spread
// over all 8 bank-groups (2-way aliasing = free, m136).
__device__ __forceinline__ int slotOf(int n, int lq) {
    return n * 4 + ((lq + (n >> 1)) & 3);
}

// async global->LDS, 16 B per lane; lds base wave-uniform, HW adds lane*16
__device__ __forceinline__ void gll16(const void* g, void* l) {
    __builtin_amdgcn_global_load_lds(
        (const __attribute__((address_space(1))) unsigned*)g,
        (__attribute__((address_space(3))) unsigned*)l, 16, 0, 0);
}

// ---------------------------------------------------------------------------
// Kernel 0: W [2048][128] fp32 -> Bt tile-major bf16 hi/lo:
// Bt[kt][part][slot][8 ushorts], kt=k/32, slot=slotOf(n,lq), elems k=lq*8+j.
// 1 MB per weight matrix. One block per kt.
// ---------------------------------------------------------------------------
__global__ __launch_bounds__(256) void bconv_tiles(
    const float* __restrict__ W, ushort* __restrict__ Bt)
{
    const int kt = blockIdx.x;       // 0..63
    const int t = threadIdx.x;
    const int n = t & 127;
    const int lq0 = (t >> 7) * 2;    // 0 or 2
    #pragma unroll
    for (int e = 0; e < 2; ++e) {
        int lq = lq0 + e;
        ushort h[8], l[8];
        #pragma unroll
        for (int j = 0; j < 8; ++j) {
            float x = W[(size_t)(kt * 32 + lq * 8 + j) * ND + n];  // coalesced
            split2(x, h[j], l[j]);
        }
        int slot = slotOf(n, lq);
        *(uint4*)&Bt[((size_t)(kt * 2 + 0) * 512 + slot) * 8] = pack8(h);
        *(uint4*)&Bt[((size_t)(kt * 2 + 1) * 512 + slot) * 8] = pack8(l);
    }
}

// ---------------------------------------------------------------------------
// Kernel 1: q = index @ Wq. 128x128 tile, waves 2x2 (64x64 each, mi=4).
// A: DIRECT global->VGPR (no LDS) + register split-bf16; B: pre-split
// tile-major via global_load_lds into double-buffered LDS (conflict-free
// swizzle). Split-K=2 -> 256 blocks; partials q1 (ws) / q2 (d_out).
// R8 BUG FIXED: B tile pointer now includes the split-K base tile (kt0).
// ---------------------------------------------------------------------------
__global__ __launch_bounds__(256) void qgemm_v2(
    const float* __restrict__ A, const ushort* __restrict__ Bt,
    float* __restrict__ q1, float* __restrict__ q2)
{
    __shared__ __align__(16) ushort BS[2][2][4096];   // [buf][hi/lo][slot*8] 32 KB

    const int tid = threadIdx.x;
    const int w = tid >> 6, lane = tid & 63;
    const int wm = w >> 1, wn = w & 1;
    const int lrow = lane & 15, lq = lane >> 4;
    const int m0 = blockIdx.x * 128;
    const int kb = blockIdx.y * (NC / 2);
    const int kt0 = blockIdx.y * ((NC / 2) / 32);   // base B tile of this K-half
    const int KITER = (NC / 2) / 32;   // 32

    const float* arow[4];
    #pragma unroll
    for (int mi = 0; mi < 4; ++mi)
        arow[mi] = A + (size_t)(m0 + wm * 64 + mi * 16 + lrow) * NC + kb + lq * 8;

    int boff[4];
    #pragma unroll
    for (int ni = 0; ni < 4; ++ni)
        boff[ni] = slotOf(wn * 64 + ni * 16 + lrow, lq) * 8;

    f32x4 acc[4][4];
    #pragma unroll
    for (int i = 0; i < 4; ++i)
        #pragma unroll
        for (int j = 0; j < 4; ++j) acc[i][j] = (f32x4){0.f, 0.f, 0.f, 0.f};

    // prologue: stage tile 0 (B) + load tile 0 (A)
    {
        const ushort* gt = Bt + (size_t)kt0 * 2 * 512 * 8;
        #pragma unroll
        for (int p = 0; p < 2; ++p)
            #pragma unroll
            for (int c2 = 0; c2 < 2; ++c2) {
                int c = 2 * w + c2;   // wave-uniform
                gll16(gt + ((size_t)p * 512 + c * 64 + lane) * 8,
                      &BS[0][p][(c * 64) * 8]);
            }
    }
    float4 fa[8];
    #pragma unroll
    for (int mi = 0; mi < 4; ++mi) {
        fa[2 * mi + 0] = *(const float4*)(arow[mi] + 0);
        fa[2 * mi + 1] = *(const float4*)(arow[mi] + 4);
    }
    __syncthreads();

    for (int kt = 0; kt < KITER; ++kt) {
        const int buf = kt & 1;
        if (kt + 1 < KITER) {   // stage next B tile into other buffer
            const ushort* gt = Bt + (size_t)(kt0 + kt + 1) * 2 * 512 * 8;
            #pragma unroll
            for (int p = 0; p < 2; ++p)
                #pragma unroll
                for (int c2 = 0; c2 < 2; ++c2) {
                    int c = 2 * w + c2;
                    gll16(gt + ((size_t)p * 512 + c * 64 + lane) * 8,
                          &BS[buf ^ 1][p][(c * 64) * 8]);
                }
        }
        // split current A into bf16 hi/lo fragments (registers only)
        short8 ah[4], al[4];
        #pragma unroll
        for (int mi = 0; mi < 4; ++mi) {
            S8U H, L;
            float xs[8] = {fa[2*mi].x, fa[2*mi].y, fa[2*mi].z, fa[2*mi].w,
                           fa[2*mi+1].x, fa[2*mi+1].y, fa[2*mi+1].z, fa[2*mi+1].w};
            #pragma unroll
            for (int j = 0; j < 8; ++j) split2(xs[j], H.u[j], L.u[j]);
            ah[mi] = H.v; al[mi] = L.v;
        }
        if (kt + 1 < KITER) {   // prefetch next A tile
            #pragma unroll
            for (int mi = 0; mi < 4; ++mi) {
                fa[2 * mi + 0] = *(const float4*)(arow[mi] + (kt + 1) * 32);
                fa[2 * mi + 1] = *(const float4*)(arow[mi] + (kt + 1) * 32 + 4);
            }
        }
        #pragma unroll
        for (int ni = 0; ni < 4; ++ni) {
            short8 bh = *(const short8*)&BS[buf][0][boff[ni]];
            short8 bl = *(const short8*)&BS[buf][1][boff[ni]];
            #pragma unroll
            for (int mi = 0; mi < 4; ++mi) {
                acc[mi][ni] = __builtin_amdgcn_mfma_f32_16x16x32_bf16(ah[mi], bh, acc[mi][ni], 0, 0, 0);
                acc[mi][ni] = __builtin_amdgcn_mfma_f32_16x16x32_bf16(ah[mi], bl, acc[mi][ni], 0, 0, 0);
                acc[mi][ni] = __builtin_amdgcn_mfma_f32_16x16x32_bf16(al[mi], bh, acc[mi][ni], 0, 0, 0);
            }
        }
        __syncthreads();
    }

    float* __restrict__ qd = blockIdx.y ? q2 : q1;
    // C/D layout: col = lane&15, row = lq*4 + r
    #pragma unroll
    for (int ni = 0; ni < 4; ++ni) {
        const int col = wn * 64 + ni * 16 + lrow;
        #pragma unroll
        for (int mi = 0; mi < 4; ++mi)
            #pragma unroll
            for (int r = 0; r < 4; ++r) {
                const int grow = m0 + wm * 64 + mi * 16 + lq * 4 + r;
                qd[(size_t)grow * ND + col] = acc[mi][ni][r];
            }
    }
}

// ---------------------------------------------------------------------------
// Kernel 1b: gathered K/V projection, same structure. M-tile 64 (waves 2x2 of
// 32x64, mi=2), grid (26, splitK=2, z=2). atomicAdd into zeroed ktop/vtop.
// R8 BUG FIXED: B tile pointer now includes the split-K base tile (kt0).
// ---------------------------------------------------------------------------
__global__ __launch_bounds__(256) void kvgemm_v2(
    const float* __restrict__ X, const ushort* __restrict__ Bkt,
    const ushort* __restrict__ Bvt, const int* __restrict__ topi,
    float* __restrict__ ktop, float* __restrict__ vtop)
{
    __shared__ __align__(16) ushort BS[2][2][4096];

    const int tid = threadIdx.x;
    const int w = tid >> 6, lane = tid & 63;
    const int wm = w >> 1, wn = w & 1;
    const int lrow = lane & 15, lq = lane >> 4;
    const int m0 = blockIdx.x * 64;
    const int kb = blockIdx.y * (NC / 2);
    const int kt0 = blockIdx.y * ((NC / 2) / 32);
    const ushort* __restrict__ Bt = blockIdx.z ? Bvt : Bkt;
    const int KITER = (NC / 2) / 32;   // 32

    const float* arow[2];
    #pragma unroll
    for (int mi = 0; mi < 2; ++mi) {
        int gi = m0 + wm * 32 + mi * 16 + lrow;
        int giC = gi < NM ? gi : NM - 1;
        int b = giC / NK, ii = giC % NK;
        int src = topi[b * KPAD + ii];
        arow[mi] = X + ((size_t)b * NT + src) * NC + kb + lq * 8;
    }
    int boff[4];
    #pragma unroll
    for (int ni = 0; ni < 4; ++ni)
        boff[ni] = slotOf(wn * 64 + ni * 16 + lrow, lq) * 8;

    f32x4 acc[2][4];
    #pragma unroll
    for (int i = 0; i < 2; ++i)
        #pragma unroll
        for (int j = 0; j < 4; ++j) acc[i][j] = (f32x4){0.f, 0.f, 0.f, 0.f};

    {
        const ushort* gt = Bt + (size_t)kt0 * 2 * 512 * 8;
        #pragma unroll
        for (int p = 0; p < 2; ++p)
            #pragma unroll
            for (int c2 = 0; c2 < 2; ++c2) {
                int c = 2 * w + c2;
                gll16(gt + ((size_t)p * 512 + c * 64 + lane) * 8,
                      &BS[0][p][(c * 64) * 8]);
            }
    }
    float4 fa[4];
    #pragma unroll
    for (int mi = 0; mi < 2; ++mi) {
        fa[2 * mi + 0] = *(const float4*)(arow[mi] + 0);
        fa[2 * mi + 1] = *(const float4*)(arow[mi] + 4);
    }
    __syncthreads();

    for (int kt = 0; kt < KITER; ++kt) {
        const int buf = kt & 1;
        if (kt + 1 < KITER) {
            const ushort* gt = Bt + (size_t)(kt0 + kt + 1) * 2 * 512 * 8;
            #pragma unroll
            for (int p = 0; p < 2; ++p)
                #pragma unroll
                for (int c2 = 0; c2 < 2; ++c2) {
                    int c = 2 * w + c2;
                    gll16(gt + ((size_t)p * 512 + c * 64 + lane) * 8,
                          &BS[buf ^ 1][p][(c * 64) * 8]);
                }
        }
        short8 ah[2], al[2];
        #pragma unroll
        for (int mi = 0; mi < 2; ++mi) {
            S8U H, L;
            float xs[8] = {fa[2*mi].x, fa[2*mi].y, fa[2*mi].z, fa[2*mi].w,
                           fa[2*mi+1].x, fa[2*mi+1].y, fa[2*mi+1].z, fa[2*mi+1].w};
            #pragma unroll
            for (int j = 0; j < 8; ++j) split2(xs[j], H.u[j], L.u[j]);
            ah[mi] = H.v; al[mi] = L.v;
        }
        if (kt + 1 < KITER) {
            #pragma unroll
            for (int mi = 0; mi < 2; ++mi) {
                fa[2 * mi + 0] = *(const float4*)(arow[mi] + (kt + 1) * 32);
                fa[2 * mi + 1] = *(const float4*)(arow[mi] + (kt + 1) * 32 + 4);
            }
        }
        #pragma unroll
        for (int ni = 0; ni < 4; ++ni) {
            short8 bh = *(const short8*)&BS[buf][0][boff[ni]];
            short8 bl = *(const short8*)&BS[buf][1][boff[ni]];
            #pragma unroll
            for (int mi = 0; mi < 2; ++mi) {
                acc[mi][ni] = __builtin_amdgcn_mfma_f32_16x16x32_bf16(ah[mi], bh, acc[mi][ni], 0, 0, 0);
                acc[mi][ni] = __builtin_amdgcn_mfma_f32_16x16x32_bf16(ah[mi], bl, acc[mi][ni], 0, 0, 0);
                acc[mi][ni] = __builtin_amdgcn_mfma_f32_16x16x32_bf16(al[mi], bh, acc[mi][ni], 0, 0, 0);
            }
        }
        __syncthreads();
    }

    float* __restrict__ dst = blockIdx.z ? vtop : ktop;
    #pragma unroll
    for (int ni = 0; ni < 4; ++ni) {
        const int col = wn * 64 + ni * 16 + lrow;
        #pragma unroll
        for (int mi = 0; mi < 2; ++mi)
            #pragma unroll
            for (int r = 0; r < 4; ++r) {
                const int grow = m0 + wm * 32 + mi * 16 + lq * 4 + r;
                if (grow < NM)
                    atomicAdd(&dst[(size_t)grow * ND + col], acc[mi][ni][r]);
            }
    }
}

// ---------------------------------------------------------------------------
// Kernel 2: q = q1 + q2 (in-place into q1) + q_norms. One wave per row.
// ---------------------------------------------------------------------------
__global__ __launch_bounds__(256) void qnorm_kernel(
    float* __restrict__ q1, const float* __restrict__ q2, float* __restrict__ qn)
{
    const int wv = (blockIdx.x * 256 + threadIdx.x) >> 6;
    const int lane = threadIdx.x & 63;
    float* r1 = q1 + (size_t)wv * ND;
    const float* r2 = q2 + (size_t)wv * ND;
    float a = r1[lane] + r2[lane];
    float b = r1[lane + 64] + r2[lane + 64];
    r1[lane] = a;
    r1[lane + 64] = b;
    float s = a * a + b * b;
    #pragma unroll
    for (int off = 32; off > 0; off >>= 1) s += __shfl_xor(s, off);
    if (lane == 0) qn[wv] = sqrtf(s);
}

// ---------------------------------------------------------------------------
// Kernel 3: exact top-k by rank counting (jax.lax.top_k tie rules).
// ---------------------------------------------------------------------------
__global__ __launch_bounds__(256) void topk_kernel(
    const float* __restrict__ qn, int* __restrict__ topi, int* __restrict__ cnt)
{
    __shared__ int rs[4][64];
    const int b = blockIdx.y;
    const int is = threadIdx.x & 63;
    const int i = blockIdx.x * 64 + is;
    const int chunk = threadIdx.x >> 6;
    const float vi = qn[(size_t)b * NT + i];
    const float4* qv = (const float4*)(qn + (size_t)b * NT + chunk * 1024);
    int rank = 0;
    #pragma unroll 4
    for (int j4 = 0; j4 < 256; ++j4) {
        float4 v = qv[j4];
        int j = chunk * 1024 + j4 * 4;
        rank += (v.x > vi || (v.x == vi && (j + 0) < i)) ? 1 : 0;
        rank += (v.y > vi || (v.y == vi && (j + 1) < i)) ? 1 : 0;
        rank += (v.z > vi || (v.z == vi && (j + 2) < i)) ? 1 : 0;
        rank += (v.w > vi || (v.w == vi && (j + 3) < i)) ? 1 : 0;
    }
    rs[chunk][is] = rank;
    __syncthreads();
    if (threadIdx.x < 64) {
        int rk = rs[0][threadIdx.x] + rs[1][threadIdx.x] + rs[2][threadIdx.x] + rs[3][threadIdx.x];
        if (rk < NK) {
            int p = atomicAdd(&cnt[b], 1);
            topi[b * KPAD + p] = blockIdx.x * 64 + threadIdx.x;
        }
    }
}

// ---------------------------------------------------------------------------
// Kernel 5: per (batch, top-k row): scores -> softmax -> PV -> scatter.
// ---------------------------------------------------------------------------
__global__ __launch_bounds__(256) void attn_kernel(
    const float* __restrict__ q, const float* __restrict__ ktop,
    const float* __restrict__ vtop, const int* __restrict__ topi,
    float* __restrict__ out)
{
    __shared__ float qs[ND];
    __shared__ float ss[KPAD];
    __shared__ float red[256];
    __shared__ float pv[2][ND];
    const int bi = blockIdx.x;
    const int b = bi / NK, i = bi % NK;
    const int t = threadIdx.x;
    const int row = topi[b * KPAD + i];
    if (t < ND) qs[t] = q[((size_t)b * NT + row) * ND + t];
    __syncthreads();

    const float scale = 0.08838834764831844f;   // 1/sqrt(128)
    float mymax = -1e30f;
    #pragma unroll
    for (int rep = 0; rep < 2; ++rep) {
        int j = t + rep * 256;
        if (j < NK) {
            const float4* kr = (const float4*)(ktop + ((size_t)b * NK + j) * ND);
            const float4* q4 = (const float4*)qs;
            float s = 0.f;
            #pragma unroll
            for (int dd = 0; dd < 32; ++dd) {
                float4 a = q4[dd], kv = kr[dd];
                s += a.x * kv.x + a.y * kv.y + a.z * kv.z + a.w * kv.w;
            }
            s *= scale;
            ss[j] = s;
            mymax = fmaxf(mymax, s);
        }
    }
    red[t] = mymax;
    __syncthreads();
    for (int off = 128; off > 0; off >>= 1) {
        if (t < off) red[t] = fmaxf(red[t], red[t + off]);
        __syncthreads();
    }
    const float mx = red[0];
    __syncthreads();

    float mysum = 0.f;
    #pragma unroll
    for (int rep = 0; rep < 2; ++rep) {
        int j = t + rep * 256;
        if (j < NK) {
            float p = __expf(ss[j] - mx);
            ss[j] = p;
            mysum += p;
        }
    }
    red[t] = mysum;
    __syncthreads();
    for (int off = 128; off > 0; off >>= 1) {
        if (t < off) red[t] += red[t + off];
        __syncthreads();
    }
    const float inv = 1.f / red[0];

    const int col = t & (ND - 1), half = t >> 7;
    float o = 0.f;
    #pragma unroll 4
    for (int j = half; j < NK; j += 2)
        o = fmaf(ss[j], vtop[((size_t)b * NK + j) * ND + col], o);
    pv[half][col] = o;
    __syncthreads();
    if (t < ND)
        out[((size_t)b * NT + row) * ND + t] = (pv[0][t] + pv[1][t]) * inv;
}

// ---------------------------------------------------------------------------
extern "C" void kernel_launch(void* const* d_in, const int* in_sizes, int n_in,
                              void* d_out, int out_size, void* d_ws, size_t ws_size,
                              hipStream_t stream)
{
    const float* index = (const float*)d_in[0];
    const float* Wq = (const float*)d_in[1];
    const float* Wk = (const float*)d_in[2];
    const float* Wv = (const float*)d_in[3];
    float* out = (float*)d_out;

    // ws: 10,137,856 B proven footprint.
    char* ws = (char*)d_ws;
    float*  q1   = (float*)(ws);                       // 8,388,608
    float*  qn   = (float*)(ws + 8388608);             //    65,536
    int*    topi = (int*)  (ws + 8454144);             //     8,192
    int*    cnt  = (int*)  (ws + 8462336);             //       256
    ushort* Bqt  = (ushort*)(ws + 8462592);            // 1,048,576 (phase 1)
    float*  ktop = (float*)(ws + 8462592);             //   837,632 (phase 2)
    float*  vtop = (float*)(ws + 9300224);             //   837,632 (phase 2)

    // d_out scratch: q2 partial (phase A), then Bkt/Bvt (phase B), then output.
    float*  q2  = (float*)d_out;
    ushort* Bkt = (ushort*)d_out;                      // 1,048,576
    ushort* Bvt = (ushort*)((char*)d_out + 1048576);   // 1,048,576

    hipMemsetAsync(cnt, 0, NB * sizeof(int), stream);

    bconv_tiles<<<dim3(64), dim3(256), 0, stream>>>(Wq, Bqt);
    qgemm_v2<<<dim3(NB * NT / 128, 2), dim3(256), 0, stream>>>(index, Bqt, q1, q2);
    qnorm_kernel<<<dim3(NB * NT / 4), dim3(256), 0, stream>>>(q1, q2, qn);
    topk_kernel<<<dim3(NT / 64, NB), dim3(256), 0, stream>>>(qn, topi, cnt);
    bconv_tiles<<<dim3(64), dim3(256), 0, stream>>>(Wk, Bkt);
    bconv_tiles<<<dim3(64), dim3(256), 0, stream>>>(Wv, Bvt);
    hipMemsetAsync(ktop, 0, 2 * 837632, stream);   // zero ktop+vtop (atomic accum)
    kvgemm_v2<<<dim3((NM + 63) / 64, 2, 2), dim3(256), 0, stream>>>(
        index, Bkt, Bvt, topi, ktop, vtop);
    hipMemsetAsync(d_out, 0, (size_t)out_size * sizeof(float), stream);
    attn_kernel<<<dim3(NM), dim3(256), 0, stream>>>(q1, ktop, vtop, topi, out);
}